// Round 2
// baseline (668.070 us; speedup 1.0000x reference)
//
#include <hip/hip_runtime.h>
#include <cstdint>
#include <cstddef>

#define D_DIM 128

typedef __attribute__((ext_vector_type(8))) __bf16 bf16x8;
typedef __attribute__((ext_vector_type(4))) float f32x4;

__device__ __forceinline__ unsigned short f2bf(float f) {
    unsigned u = __builtin_bit_cast(unsigned, f);
    u += 0x7FFFu + ((u >> 16) & 1u);   // round-to-nearest-even (no NaN in data)
    return (unsigned short)(u >> 16);
}
__device__ __forceinline__ float bf2f(unsigned short h) {
    unsigned u = ((unsigned)h) << 16;
    return __builtin_bit_cast(float, u);
}

// ---------------------------------------------------------------------------
// Prepass: fp32 -> bf16 conversion + squared norms of the bf16-rounded rows.
// One wave per row (128 floats): lane loads float2, packs 2 bf16, shuffle-reduce.
// ---------------------------------------------------------------------------
__global__ __launch_bounds__(256) void prep_kernel(
    const float* __restrict__ x, const float* __restrict__ w,
    unsigned short* __restrict__ xb, unsigned short* __restrict__ wb,
    float* __restrict__ xsq, float* __restrict__ wsq,
    int n_rows_x, int n_rows_w)
{
    const int wave = threadIdx.x >> 6;
    const int lane = threadIdx.x & 63;
    int row = blockIdx.x * 4 + wave;
    const float* src; unsigned short* dst; float* nrm; int r;
    if (row < n_rows_x) { src = x; dst = xb; nrm = xsq; r = row; }
    else {
        r = row - n_rows_x;
        if (r >= n_rows_w) return;
        src = w; dst = wb; nrm = wsq;
    }
    const float2* srow = reinterpret_cast<const float2*>(src + (size_t)r * D_DIM);
    float2 v = srow[lane];
    unsigned short b0 = f2bf(v.x), b1 = f2bf(v.y);
    float f0 = bf2f(b0), f1 = bf2f(b1);
    unsigned pack = (unsigned)b0 | ((unsigned)b1 << 16);
    reinterpret_cast<unsigned*>(dst + (size_t)r * D_DIM)[lane] = pack;
    float s = f0 * f0 + f1 * f1;
    #pragma unroll
    for (int off = 32; off > 0; off >>= 1) s += __shfl_xor(s, off, 64);
    if (lane == 0) nrm[r] = s;
}

// ---------------------------------------------------------------------------
// GEMM: out[n,c] = xsq[n] + wsq[c] - 2 * <x[n,:], w[c,:]>   (bf16 MFMA)
// NO LDS staging, NO __syncthreads: K=128 means each MFMA fragment is a
// contiguous 16 B chunk of row-major global memory -> direct dwordx4 loads,
// freely pipelined by the compiler with fine-grained vmcnt. x/w tiles are
// L3/L2-resident so cache re-reads across blocks are cheap.
// 128x128 tile / block (4 waves, each a 64x64 subtile).
// Epilogue: wave-private LDS transpose (stride-68 pad, 2-way conflicts = free;
// DS ops are in-order within a wave, so no barrier), fused distance formula,
// fully-coalesced float4 stores (256 B contiguous per row segment).
// ---------------------------------------------------------------------------
#define TLDS_STRIDE 68   // words; 272 B row pitch, 16B-aligned, breaks bank patterns

__global__ __launch_bounds__(256) void rbf_gemm(
    const unsigned short* __restrict__ xb, const unsigned short* __restrict__ wb,
    const float* __restrict__ xsq, const float* __restrict__ wsq,
    float* __restrict__ out, int C_total)
{
    __shared__ float tlds[4][16 * TLDS_STRIDE];   // 4 x 4352 B = 17.4 KB

    const int tid    = threadIdx.x;
    const int wave   = tid >> 6;
    const int lane   = tid & 63;
    const int lane16 = lane & 15;
    const int quad   = lane >> 4;

    const long c0 = (long)blockIdx.x * 128;   // c-tile fastest -> x-tile L2/L3 reuse
    const long m0 = (long)blockIdx.y * 128;

    const int wm = (wave & 1) * 64;
    const int wc = (wave >> 1) * 64;

    // Fragment base pointers: A frag (mt,kk) = 16 B at row (m0+wm+mt*16+lane16),
    // byte offset kk*2 + quad*16 within the 256 B row. Same shape for B.
    const unsigned short* aBase = xb + ((size_t)(m0 + wm) + lane16) * D_DIM + quad * 8;
    const unsigned short* bBase = wb + ((size_t)(c0 + wc) + lane16) * D_DIM + quad * 8;

    f32x4 acc[4][4];
    #pragma unroll
    for (int i = 0; i < 4; ++i)
        #pragma unroll
        for (int j = 0; j < 4; ++j)
            acc[i][j] = (f32x4){0.f, 0.f, 0.f, 0.f};

    #pragma unroll
    for (int kk = 0; kk < 128; kk += 32) {
        bf16x8 a[4], b[4];
        #pragma unroll
        for (int mt = 0; mt < 4; ++mt)
            a[mt] = *reinterpret_cast<const bf16x8*>(aBase + (size_t)mt * 16 * D_DIM + kk);
        #pragma unroll
        for (int ct = 0; ct < 4; ++ct)
            b[ct] = *reinterpret_cast<const bf16x8*>(bBase + (size_t)ct * 16 * D_DIM + kk);
        #pragma unroll
        for (int mt = 0; mt < 4; ++mt)
            #pragma unroll
            for (int ct = 0; ct < 4; ++ct)
                acc[mt][ct] = __builtin_amdgcn_mfma_f32_16x16x32_bf16(
                    a[mt], b[ct], acc[mt][ct], 0, 0, 0);
    }

    // --- epilogue ---
    // wsq for this wave's 64 cols as seen post-transpose: cols (lane16*4 .. +3)
    const f32x4 wq = *reinterpret_cast<const f32x4*>(&wsq[c0 + wc + lane16 * 4]);
    float* buf = tlds[wave];

    #pragma unroll
    for (int mt = 0; mt < 4; ++mt) {
        // write C-layout slab (16 rows x 64 cols) into padded LDS
        #pragma unroll
        for (int ct = 0; ct < 4; ++ct)
            #pragma unroll
            for (int i = 0; i < 4; ++i)
                buf[(quad * 4 + i) * TLDS_STRIDE + ct * 16 + lane16] = acc[mt][ct][i];

        // read back transposed: lane covers 16 consecutive bytes of a row
        #pragma unroll
        for (int j = 0; j < 4; ++j) {
            const int row_local = j * 4 + quad;
            f32x4 v = *reinterpret_cast<const f32x4*>(
                &buf[row_local * TLDS_STRIDE + lane16 * 4]);
            const long row = m0 + wm + mt * 16 + row_local;
            const float xs = xsq[row];
            f32x4 r;
            #pragma unroll
            for (int k = 0; k < 4; ++k)
                r[k] = xs + wq[k] - 2.0f * v[k];
            *reinterpret_cast<f32x4*>(&out[row * (long)C_total + c0 + wc + lane16 * 4]) = r;
        }
    }
}

extern "C" void kernel_launch(void* const* d_in, const int* in_sizes, int n_in,
                              void* d_out, int out_size, void* d_ws, size_t ws_size,
                              hipStream_t stream) {
    const float* x = (const float*)d_in[0];
    const float* w = (const float*)d_in[1];
    float* out = (float*)d_out;

    const int N = in_sizes[0] / D_DIM;   // 131072
    const int C = in_sizes[1] / D_DIM;   // 1024

    // workspace layout: xb bf16[N*128] | wb bf16[C*128] | xsq f32[N] | wsq f32[C]
    unsigned short* xb = (unsigned short*)d_ws;
    unsigned short* wb = xb + (size_t)N * D_DIM;
    float* xsq = (float*)(wb + (size_t)C * D_DIM);
    float* wsq = xsq + N;

    const int rows = N + C;
    prep_kernel<<<(rows + 3) / 4, 256, 0, stream>>>(x, w, xb, wb, xsq, wsq, N, C);

    dim3 grid(C / 128, N / 128);   // (8, 1024)
    rbf_gemm<<<grid, 256, 0, stream>>>(xb, wb, xsq, wsq, out, C);
}